// Round 1
// baseline (543.882 us; speedup 1.0000x reference)
//
#include <hip/hip_runtime.h>
#include <math.h>

#define NC 19
#define H  320
#define W  2048
#define HW (H * W)         // 655360
#define P  1280            // 10 * 128
#define NB 8

// Kernel 1: per (b, hh'=0..9, ww=0..127) compute argmax_c of 16x16 block sums
// of raw label (log_softmax + mean is argmax-equivalent; see analysis).
// One wave (64 lanes) per output; each lane loads one float4 per channel.
__global__ __launch_bounds__(256) void pool_argmax_kernel(
    const float* __restrict__ label, int* __restrict__ lab)
{
    int wid  = blockIdx.x * 4 + (threadIdx.x >> 6);   // 0..10239
    int lane = threadIdx.x & 63;

    int ww = wid & 127;
    int t  = wid >> 7;          // b*10 + hp
    int hp = t % 10;
    int b  = t / 10;

    int h0 = (hp + 10) * 16;    // rows 160..319 only
    int w0 = ww * 16;

    const float* base = label + (size_t)b * NC * HW + (size_t)h0 * W + w0;
    int r  = lane >> 2;         // row within block, 0..15
    int c4 = lane & 3;          // float4 column, 0..3
    const float* p0 = base + (size_t)r * W + (size_t)c4 * 4;

    float best  = -3.4e38f;
    int   bestc = 0;
    for (int c = 0; c < NC; ++c) {
        float4 v = *(const float4*)(p0 + (size_t)c * HW);
        float s = (v.x + v.y) + (v.z + v.w);
        #pragma unroll
        for (int off = 32; off; off >>= 1)
            s += __shfl_down(s, off, 64);
        s = __shfl(s, 0, 64);
        if (s > best) { best = s; bestc = c; }   // strict > == first-max tie-break
    }
    if (lane == 0) lab[wid] = bestc;
}

// Kernel 2: one 320-thread block per (b, i) row of e / attention_map.
// Each thread handles 4 consecutive j via float4/int4.
__global__ __launch_bounds__(320) void e_softmax_kernel(
    const float* __restrict__ energy, const int* __restrict__ lab,
    float* __restrict__ e_out, float* __restrict__ attn_out)
{
    int row = blockIdx.x;           // 0..10239 = b*1280 + i
    int t   = threadIdx.x;          // 0..319
    int b   = row / P;
    int i   = row - b * P;

    int li = lab[b * P + i];
    int4   lj = ((const int4*)(lab + b * P))[t];
    float4 en = ((const float4*)(energy + (size_t)row * P))[t];

    int   lv[4] = { lj.x, lj.y, lj.z, lj.w };
    float ev[4] = { en.x, en.y, en.z, en.w };
    float v[4];
    #pragma unroll
    for (int m = 0; m < 4; ++m) {
        bool same = (lv[m] == li);
        v[m] = same ? (ev[m] < 0.f ?  0.5f : ev[m])
                    : (ev[m] > 0.f ? -0.5f : ev[m]);
    }

    // --- block max reduction (5 waves) ---
    float mx = fmaxf(fmaxf(v[0], v[1]), fmaxf(v[2], v[3]));
    #pragma unroll
    for (int off = 32; off; off >>= 1)
        mx = fmaxf(mx, __shfl_down(mx, off, 64));
    __shared__ float redmax[5];
    __shared__ float redsum[5];
    int wv = t >> 6;
    if ((t & 63) == 0) redmax[wv] = mx;
    __syncthreads();
    mx = fmaxf(fmaxf(fmaxf(redmax[0], redmax[1]),
                     fmaxf(redmax[2], redmax[3])), redmax[4]);

    // --- exp + block sum reduction ---
    float ex[4];
    float s = 0.f;
    #pragma unroll
    for (int m = 0; m < 4; ++m) { ex[m] = __expf(v[m] - mx); s += ex[m]; }
    #pragma unroll
    for (int off = 32; off; off >>= 1)
        s += __shfl_down(s, off, 64);
    if ((t & 63) == 0) redsum[wv] = s;
    __syncthreads();
    s = (redsum[0] + redsum[1]) + (redsum[2] + redsum[3]) + redsum[4];
    float inv = 1.0f / s;

    float4 eo = make_float4(v[0], v[1], v[2], v[3]);
    float4 ao = make_float4(ex[0] * inv, ex[1] * inv, ex[2] * inv, ex[3] * inv);
    ((float4*)(e_out    + (size_t)row * P))[t] = eo;
    ((float4*)(attn_out + (size_t)row * P))[t] = ao;
}

extern "C" void kernel_launch(void* const* d_in, const int* in_sizes, int n_in,
                              void* d_out, int out_size, void* d_ws, size_t ws_size,
                              hipStream_t stream) {
    const float* label  = (const float*)d_in[0];   // [8,19,320,2048] fp32
    const float* energy = (const float*)d_in[1];   // [8,1280,1280]  fp32

    float* e_out    = (float*)d_out;                       // [8,1280,1280]
    float* attn_out = e_out + (size_t)NB * P * P;          // [8,1280,1280]
    int*   lab      = (int*)d_ws;                          // [8,1280]

    hipLaunchKernelGGL(pool_argmax_kernel, dim3(2560), dim3(256), 0, stream,
                       label, lab);
    hipLaunchKernelGGL(e_softmax_kernel, dim3(NB * P), dim3(320), 0, stream,
                       energy, lab, e_out, attn_out);
}

// Round 2
// 527.342 us; speedup vs baseline: 1.0314x; 1.0314x over previous
//
#include <hip/hip_runtime.h>
#include <math.h>

#define NC 19
#define H  320
#define W  2048
#define HW (H * W)         // 655360
#define P  1280            // 10 * 128
#define NB 8

// Kernel 1: argmax_c of 16x16 block sums of raw label (log_softmax + block-mean
// is argmax-equivalent: pooled = mean(x_c) - mean(lse), second term c-independent).
// Only hh in [10,20) survives the slice -> label rows 160..319.
// One wave handles TWO adjacent ww blocks: per row a full aligned 128 B segment.
// lane -> r = lane>>3 (8 rows/load, 2 loads/channel), c4 = lane&7 (8 float4 = 128 B).
// sub-block = c4>>2. Butterfly shfl_xor over bits {0,1,3,4,5} reduces each half.
__global__ __launch_bounds__(256) void pool_argmax_kernel(
    const float* __restrict__ label, int* __restrict__ lab)
{
    int gw   = blockIdx.x * 4 + (threadIdx.x >> 6);   // 0..5119 wave id
    int lane = threadIdx.x & 63;

    int wp = gw & 63;           // ww pair index, blocks 2*wp, 2*wp+1
    int t  = gw >> 6;           // b*10 + hp
    int hp = t % 10;
    int b  = t / 10;

    int h0 = (hp + 10) * 16;    // rows 160..319 only
    int w0 = wp * 32;           // 2 blocks = 32 floats = 128 B

    int r  = lane >> 3;         // 0..7
    int c4 = lane & 7;          // 0..7 float4 within 128 B row segment

    const float* p0 = label + (size_t)b * NC * HW + (size_t)(h0 + r) * W
                    + (size_t)w0 + (size_t)c4 * 4;

    float best  = -3.4e38f;
    int   bestc = 0;
    for (int c = 0; c < NC; ++c) {
        const float* pc = p0 + (size_t)c * HW;
        float4 v0 = *(const float4*)(pc);            // rows h0+r
        float4 v1 = *(const float4*)(pc + 8 * W);    // rows h0+8+r
        float s = ((v0.x + v0.y) + (v0.z + v0.w))
                + ((v1.x + v1.y) + (v1.z + v1.w));
        // butterfly over lane bits 0,1 (c4 within half) and 3,4,5 (rows)
        s += __shfl_xor(s, 1, 64);
        s += __shfl_xor(s, 2, 64);
        s += __shfl_xor(s, 8, 64);
        s += __shfl_xor(s, 16, 64);
        s += __shfl_xor(s, 32, 64);
        if (s > best) { best = s; bestc = c; }   // strict > == first-max tie-break
    }
    // lane 0 holds block sub=0 sum, lane 4 holds block sub=1 sum
    if (lane == 0) lab[t * 128 + wp * 2]     = bestc;
    if (lane == 4) lab[t * 128 + wp * 2 + 1] = bestc;
}

// Kernel 2: one 320-thread block per (b, i) row of e / attention_map.
// Each thread handles 4 consecutive j via float4/int4.
__global__ __launch_bounds__(320) void e_softmax_kernel(
    const float* __restrict__ energy, const int* __restrict__ lab,
    float* __restrict__ e_out, float* __restrict__ attn_out)
{
    int row = blockIdx.x;           // 0..10239 = b*1280 + i
    int t   = threadIdx.x;          // 0..319
    int b   = row / P;
    int i   = row - b * P;

    int li = lab[b * P + i];
    int4   lj = ((const int4*)(lab + b * P))[t];
    float4 en = ((const float4*)(energy + (size_t)row * P))[t];

    int   lv[4] = { lj.x, lj.y, lj.z, lj.w };
    float ev[4] = { en.x, en.y, en.z, en.w };
    float v[4];
    #pragma unroll
    for (int m = 0; m < 4; ++m) {
        bool same = (lv[m] == li);
        v[m] = same ? (ev[m] < 0.f ?  0.5f : ev[m])
                    : (ev[m] > 0.f ? -0.5f : ev[m]);
    }

    // --- block max reduction (5 waves) ---
    float mx = fmaxf(fmaxf(v[0], v[1]), fmaxf(v[2], v[3]));
    #pragma unroll
    for (int off = 32; off; off >>= 1)
        mx = fmaxf(mx, __shfl_xor(mx, off, 64));
    __shared__ float redmax[5];
    __shared__ float redsum[5];
    int wv = t >> 6;
    if ((t & 63) == 0) redmax[wv] = mx;
    __syncthreads();
    mx = fmaxf(fmaxf(fmaxf(redmax[0], redmax[1]),
                     fmaxf(redmax[2], redmax[3])), redmax[4]);

    // --- exp + block sum reduction ---
    float ex[4];
    float s = 0.f;
    #pragma unroll
    for (int m = 0; m < 4; ++m) { ex[m] = __expf(v[m] - mx); s += ex[m]; }
    #pragma unroll
    for (int off = 32; off; off >>= 1)
        s += __shfl_xor(s, off, 64);
    if ((t & 63) == 0) redsum[wv] = s;
    __syncthreads();
    s = (redsum[0] + redsum[1]) + (redsum[2] + redsum[3]) + redsum[4];
    float inv = 1.0f / s;

    float4 eo = make_float4(v[0], v[1], v[2], v[3]);
    float4 ao = make_float4(ex[0] * inv, ex[1] * inv, ex[2] * inv, ex[3] * inv);
    ((float4*)(e_out    + (size_t)row * P))[t] = eo;
    ((float4*)(attn_out + (size_t)row * P))[t] = ao;
}

extern "C" void kernel_launch(void* const* d_in, const int* in_sizes, int n_in,
                              void* d_out, int out_size, void* d_ws, size_t ws_size,
                              hipStream_t stream) {
    const float* label  = (const float*)d_in[0];   // [8,19,320,2048] fp32
    const float* energy = (const float*)d_in[1];   // [8,1280,1280]  fp32

    float* e_out    = (float*)d_out;                       // [8,1280,1280]
    float* attn_out = e_out + (size_t)NB * P * P;          // [8,1280,1280]
    int*   lab      = (int*)d_ws;                          // [8,1280]

    hipLaunchKernelGGL(pool_argmax_kernel, dim3(1280), dim3(256), 0, stream,
                       label, lab);
    hipLaunchKernelGGL(e_softmax_kernel, dim3(NB * P), dim3(320), 0, stream,
                       energy, lab, e_out, attn_out);
}